// Round 5
// baseline (502.641 us; speedup 1.0000x reference)
//
#include <hip/hip_runtime.h>
#include <hip/hip_bf16.h>
#include <cstdint>
#include <cstddef>

#define NN 8192
#define FIN 256
#define FOUT 64
#define ALPHA_SLOPE 0.2f
#define EXP_M10 4.5399929762484854e-05f   // exp(-10)

#define JSPLIT 2    // j-splits in k_pv
#define CP 68       // slab column pitch (64 feats + 1 denom + pad)

typedef short s16x8 __attribute__((ext_vector_type(8)));
typedef float f32x4 __attribute__((ext_vector_type(4)));
typedef int   i32x4 __attribute__((ext_vector_type(4)));

__device__ __forceinline__ unsigned short f2bf(float x) {
    union { float f; uint32_t u; } v; v.f = x;
    uint32_t u = v.u;
    return (unsigned short)((u + 0x7FFFu + ((u >> 16) & 1u)) >> 16);  // RNE
}

// ---------------- Kernel 1: h = input@W, s1 = h@a1, s2 = h@a2, htg = bf16(h)^T ----
__global__ __launch_bounds__(256) void k_h(
    const float* __restrict__ input, const float* __restrict__ W,
    const float* __restrict__ a,
    unsigned short* __restrict__ htg, float* __restrict__ s1, float* __restrict__ s2)
{
    __shared__ __align__(16) unsigned short tile[64][28];
    const int wid  = threadIdx.x >> 6;
    const int lane = threadIdx.x & 63;
    const int i0   = blockIdx.x * 16;
    const int r0   = wid * 4;
    const float* inb = input + (size_t)(i0 + r0) * FIN;

    float acc0 = 0.f, acc1 = 0.f, acc2 = 0.f, acc3 = 0.f;
    #pragma unroll 4
    for (int c = 0; c < FIN; c += 4) {
        float w0 = W[(c + 0) * FOUT + lane];
        float w1 = W[(c + 1) * FOUT + lane];
        float w2 = W[(c + 2) * FOUT + lane];
        float w3 = W[(c + 3) * FOUT + lane];
        float4 x0 = *(const float4*)(inb + 0 * FIN + c);
        float4 x1 = *(const float4*)(inb + 1 * FIN + c);
        float4 x2 = *(const float4*)(inb + 2 * FIN + c);
        float4 x3 = *(const float4*)(inb + 3 * FIN + c);
        acc0 = fmaf(x0.x, w0, fmaf(x0.y, w1, fmaf(x0.z, w2, fmaf(x0.w, w3, acc0))));
        acc1 = fmaf(x1.x, w0, fmaf(x1.y, w1, fmaf(x1.z, w2, fmaf(x1.w, w3, acc1))));
        acc2 = fmaf(x2.x, w0, fmaf(x2.y, w1, fmaf(x2.z, w2, fmaf(x2.w, w3, acc2))));
        acc3 = fmaf(x3.x, w0, fmaf(x3.y, w1, fmaf(x3.z, w2, fmaf(x3.w, w3, acc3))));
    }

    const float a1v = a[lane], a2v = a[FOUT + lane];
    float accs[4] = {acc0, acc1, acc2, acc3};
    #pragma unroll
    for (int r = 0; r < 4; ++r) {
        float v1 = accs[r] * a1v;
        float v2 = accs[r] * a2v;
        #pragma unroll
        for (int off = 32; off; off >>= 1) {
            v1 += __shfl_xor(v1, off);
            v2 += __shfl_xor(v2, off);
        }
        if (lane == 0) { s1[i0 + r0 + r] = v1; s2[i0 + r0 + r] = v2; }
        tile[lane][r0 + r] = f2bf(accs[r]);
    }
    __syncthreads();

    const int feat = threadIdx.x >> 2;
    const int cg   = (threadIdx.x & 3) * 4;
    uint2 q = *(const uint2*)&tile[feat][cg];
    *(uint2*)(htg + (size_t)feat * NN + i0 + cg) = q;
}

// ---------------- Kernel 2a: k_score — pure streaming adj -> bf16 weights ---------
// Copy-shaped: grid covers the 64M elements linearly; each thread does 16
// consecutive elements (4 independent int4 loads), writes 2 swizzled 16B chunks.
// Row swizzle: within row i, global chunk position p holds logical chunk p^(i&7),
// so k_pv can stage rows linearly and read LDS conflict-free.
__global__ __launch_bounds__(256) void k_score(
    const int* __restrict__ adj,
    const float* __restrict__ s1g, const float* __restrict__ s2g,
    unsigned short* __restrict__ wg)
{
    const int tid = blockIdx.x * 256 + threadIdx.x;   // 0..524287
    #pragma unroll 2
    for (int s = 0; s < 8; ++s) {
        const size_t base = ((size_t)s * 524288 + tid) * 16;
        const int i = (int)(base >> 13);
        const int j = (int)(base & 8191);
        const float s1v = s1g[i];
        const int*   ap  = adj + base;
        const float* s2p = s2g + j;

        i32x4 a0 = *(const i32x4*)(ap + 0);
        i32x4 a1 = *(const i32x4*)(ap + 4);
        i32x4 a2 = *(const i32x4*)(ap + 8);
        i32x4 a3 = *(const i32x4*)(ap + 12);
        float4 v0 = *(const float4*)(s2p + 0);
        float4 v1 = *(const float4*)(s2p + 4);
        float4 v2 = *(const float4*)(s2p + 8);
        float4 v3 = *(const float4*)(s2p + 12);

        float w[16];
        {
            float xs[16] = {
                s1v+v0.x, s1v+v0.y, s1v+v0.z, s1v+v0.w,
                s1v+v1.x, s1v+v1.y, s1v+v1.z, s1v+v1.w,
                s1v+v2.x, s1v+v2.y, s1v+v2.z, s1v+v2.w,
                s1v+v3.x, s1v+v3.y, s1v+v3.z, s1v+v3.w };
            int ad[16] = {
                a0.x,a0.y,a0.z,a0.w, a1.x,a1.y,a1.z,a1.w,
                a2.x,a2.y,a2.z,a2.w, a3.x,a3.y,a3.z,a3.w };
            #pragma unroll
            for (int e = 0; e < 16; ++e) {
                float x = xs[e];
                w[e] = (ad[e] > 0) ? __expf(fmaxf(x, ALPHA_SLOPE * x)) : EXP_M10;
            }
        }

        uint4 pk0, pk1;
        pk0.x = (unsigned)f2bf(w[0])  | ((unsigned)f2bf(w[1])  << 16);
        pk0.y = (unsigned)f2bf(w[2])  | ((unsigned)f2bf(w[3])  << 16);
        pk0.z = (unsigned)f2bf(w[4])  | ((unsigned)f2bf(w[5])  << 16);
        pk0.w = (unsigned)f2bf(w[6])  | ((unsigned)f2bf(w[7])  << 16);
        pk1.x = (unsigned)f2bf(w[8])  | ((unsigned)f2bf(w[9])  << 16);
        pk1.y = (unsigned)f2bf(w[10]) | ((unsigned)f2bf(w[11]) << 16);
        pk1.z = (unsigned)f2bf(w[12]) | ((unsigned)f2bf(w[13]) << 16);
        pk1.w = (unsigned)f2bf(w[14]) | ((unsigned)f2bf(w[15]) << 16);

        const int x7 = i & 7;
        const int c0 = j >> 3;              // even
        unsigned short* rowp = wg + (size_t)i * NN;
        *(uint4*)(rowp + (size_t)(c0       ^ x7) * 8) = pk0;
        *(uint4*)(rowp + (size_t)((c0 + 1) ^ x7) * 8) = pk1;
    }
}

// ---------------- Kernel 2b: k_pv — Wg(8192x8192 bf16) @ [h | 1] -------------------
// Block: 16-row i-tile x 4096-col j-range (4 waves). Per 512-col tile: stage 16
// rows x 1KB from Wg into LDS (sequential bursts, pre-swizzled), then each wave
// handles 4 of 16 kk steps x 5 MFMA (4 feat blocks + denominator). Wave partials
// reduced through LDS at the end.
__global__ __launch_bounds__(256) void k_pv(
    const unsigned short* __restrict__ wg,
    const unsigned short* __restrict__ htg,
    float* __restrict__ slabs)
{
    __shared__ __align__(16) unsigned char smem[18432];   // 16KB stage | 17.4KB reduce
    unsigned short* Wt = (unsigned short*)smem;

    const int t    = threadIdx.x;
    const int wid  = t >> 6;
    const int lane = t & 63;
    const int bi   = blockIdx.x >> 1;       // i-tile (0..511)
    const int js   = blockIdx.x & 1;        // j-split (0..1)
    const int i0   = bi * 16;
    const int jbase = js * (NN / JSPLIT);
    const int m    = lane & 15;
    const int quad = lane >> 4;

    const short bd = (m == 0) ? (short)0x3F80 : (short)0;  // bf16 1.0 / 0
    const s16x8 bden = {bd, bd, bd, bd, bd, bd, bd, bd};

    f32x4 acc0 = {0,0,0,0}, acc1 = {0,0,0,0}, acc2 = {0,0,0,0},
          acc3 = {0,0,0,0}, acc4 = {0,0,0,0};

    for (int tile = 0; tile < 8; ++tile) {
        const int j0 = jbase + tile * 512;
        __syncthreads();   // previous tile's readers done

        // stage: wave wid loads rows 4*wid..4*wid+3, 1KB sequential each
        #pragma unroll
        for (int rr = 0; rr < 4; ++rr) {
            const int row = wid * 4 + rr;
            const unsigned short* src = wg + (size_t)(i0 + row) * NN + j0 + lane * 8;
            s16x8 val = *(const s16x8*)src;
            *(s16x8*)&Wt[(row * 64 + lane) * 8] = val;
        }
        __syncthreads();

        // mfma: wave wid handles kk = 4*wid .. 4*wid+3
        #pragma unroll
        for (int kq = 0; kq < 4; ++kq) {
            const int kk = wid * 4 + kq;
            const int pos = (kk * 4 + quad) ^ (m & 7);
            s16x8 af = *(const s16x8*)&Wt[(m * 64 + pos) * 8];
            const unsigned short* hp = htg + (size_t)m * NN + j0 + kk * 32 + quad * 8;
            s16x8 b0 = *(const s16x8*)(hp);
            s16x8 b1 = *(const s16x8*)(hp + (size_t)16 * NN);
            s16x8 b2 = *(const s16x8*)(hp + (size_t)32 * NN);
            s16x8 b3 = *(const s16x8*)(hp + (size_t)48 * NN);
            acc0 = __builtin_amdgcn_mfma_f32_16x16x32_bf16(af, b0,   acc0, 0, 0, 0);
            acc1 = __builtin_amdgcn_mfma_f32_16x16x32_bf16(af, b1,   acc1, 0, 0, 0);
            acc2 = __builtin_amdgcn_mfma_f32_16x16x32_bf16(af, b2,   acc2, 0, 0, 0);
            acc3 = __builtin_amdgcn_mfma_f32_16x16x32_bf16(af, b3,   acc3, 0, 0, 0);
            acc4 = __builtin_amdgcn_mfma_f32_16x16x32_bf16(af, bden, acc4, 0, 0, 0);
        }
    }

    // reduce the 4 waves' kk-partials through LDS
    __syncthreads();
    float* red = (float*)smem;               // 4 x 16 x CP floats = 17.4 KB
    float* myred = red + wid * 16 * CP;
    #pragma unroll
    for (int reg = 0; reg < 4; ++reg) {
        const int r = quad * 4 + reg;
        myred[r * CP +  0 + m] = acc0[reg];
        myred[r * CP + 16 + m] = acc1[reg];
        myred[r * CP + 32 + m] = acc2[reg];
        myred[r * CP + 48 + m] = acc3[reg];
        if (m == 0) myred[r * CP + 64] = acc4[reg];
    }
    __syncthreads();

    float* slab = slabs + (size_t)js * ((size_t)NN * CP);
    for (int idx = t; idx < 16 * 65; idx += 256) {
        const int r = idx / 65, c = idx % 65;
        float s = red[0 * 16 * CP + r * CP + c] + red[1 * 16 * CP + r * CP + c]
                + red[2 * 16 * CP + r * CP + c] + red[3 * 16 * CP + r * CP + c];
        slab[(size_t)(i0 + r) * CP + c] = s;
    }
}

// ---------------- Kernel 3: reduce splits, normalize, ELU --------------------------
__global__ __launch_bounds__(256) void k_norm(
    const float* __restrict__ slabs, float* __restrict__ out)
{
    int gid = blockIdx.x * 256 + threadIdx.x;
    int i = gid >> 6, k = gid & 63;
    float num = 0.f, den = 0.f;
    #pragma unroll
    for (int js = 0; js < JSPLIT; ++js) {
        const float* row = slabs + (size_t)js * ((size_t)NN * CP) + (size_t)i * CP;
        num += row[k];
        den += row[64];
    }
    float v = num / den;
    out[gid] = (v > 0.f) ? v : (__expf(v) - 1.f);
}

// ---------------- launch -----------------------------------------------------------
extern "C" void kernel_launch(void* const* d_in, const int* in_sizes, int n_in,
                              void* d_out, int out_size, void* d_ws, size_t ws_size,
                              hipStream_t stream) {
    const float* input = (const float*)d_in[0];
    const int*   adj   = (const int*)d_in[1];
    const float* W     = (const float*)d_in[2];
    const float* a     = (const float*)d_in[3];
    float* out = (float*)d_out;

    char* ws = (char*)d_ws;
    unsigned short* wg = (unsigned short*)ws;                   // 134.2 MB
    size_t off = (size_t)NN * NN * sizeof(unsigned short);
    float* slabs = (float*)(ws + off);
    off += (size_t)JSPLIT * NN * CP * sizeof(float);            // 4.5 MB
    unsigned short* htg = (unsigned short*)(ws + off);
    off += (size_t)FOUT * NN * sizeof(unsigned short);          // 1 MB
    float* s1 = (float*)(ws + off); off += NN * sizeof(float);
    float* s2 = (float*)(ws + off);

    k_h    <<<NN / 16, 256, 0, stream>>>(input, W, a, htg, s1, s2);
    k_score<<<2048, 256, 0, stream>>>(adj, s1, s2, wg);
    k_pv   <<<(NN / 16) * JSPLIT, 256, 0, stream>>>(wg, htg, slabs);
    k_norm <<<NN * FOUT / 256, 256, 0, stream>>>(slabs, out);
}

// Round 6
// 419.176 us; speedup vs baseline: 1.1991x; 1.1991x over previous
//
#include <hip/hip_runtime.h>
#include <hip/hip_bf16.h>
#include <cstdint>
#include <cstddef>

#define NN 8192
#define FIN 256
#define FOUT 64
#define ALPHA_SLOPE 0.2f
#define EXP_M10 4.5399929762484854e-05f   // exp(-10)

#define TILE_COLS 512
#define NTILES (NN / TILE_COLS)          // 16
#define ROW_PITCH 2064                   // bytes: 2048 data + 16 pad (2-way-bank-free, 16B aligned)
#define BUF_BYTES (16 * ROW_PITCH)       // 33024
#define CP 68                            // reduction row pitch (floats)

typedef short s16x8 __attribute__((ext_vector_type(8)));
typedef float f32x4 __attribute__((ext_vector_type(4)));
typedef int   i32x4 __attribute__((ext_vector_type(4)));

__device__ __forceinline__ unsigned short f2bf(float x) {
    union { float f; uint32_t u; } v; v.f = x;
    uint32_t u = v.u;
    return (unsigned short)((u + 0x7FFFu + ((u >> 16) & 1u)) >> 16);  // RNE
}

// async 16B/lane global->LDS: lds dest = wave-uniform base + lane*16
__device__ __forceinline__ void gl_lds16(const int* g, void* l) {
    __builtin_amdgcn_global_load_lds(
        (const __attribute__((address_space(1))) unsigned int*)g,
        (__attribute__((address_space(3))) unsigned int*)l,
        16, 0, 0);
}

// ---------------- Kernel 1: h = input@W, s1 = h@a1, s2 = h@a2, htg = bf16(h)^T ----
__global__ __launch_bounds__(256) void k_h(
    const float* __restrict__ input, const float* __restrict__ W,
    const float* __restrict__ a,
    unsigned short* __restrict__ htg, float* __restrict__ s1, float* __restrict__ s2)
{
    __shared__ __align__(16) unsigned short tile[64][28];
    const int wid  = threadIdx.x >> 6;
    const int lane = threadIdx.x & 63;
    const int i0   = blockIdx.x * 16;
    const int r0   = wid * 4;
    const float* inb = input + (size_t)(i0 + r0) * FIN;

    float acc0 = 0.f, acc1 = 0.f, acc2 = 0.f, acc3 = 0.f;
    #pragma unroll 4
    for (int c = 0; c < FIN; c += 4) {
        float w0 = W[(c + 0) * FOUT + lane];
        float w1 = W[(c + 1) * FOUT + lane];
        float w2 = W[(c + 2) * FOUT + lane];
        float w3 = W[(c + 3) * FOUT + lane];
        float4 x0 = *(const float4*)(inb + 0 * FIN + c);
        float4 x1 = *(const float4*)(inb + 1 * FIN + c);
        float4 x2 = *(const float4*)(inb + 2 * FIN + c);
        float4 x3 = *(const float4*)(inb + 3 * FIN + c);
        acc0 = fmaf(x0.x, w0, fmaf(x0.y, w1, fmaf(x0.z, w2, fmaf(x0.w, w3, acc0))));
        acc1 = fmaf(x1.x, w0, fmaf(x1.y, w1, fmaf(x1.z, w2, fmaf(x1.w, w3, acc1))));
        acc2 = fmaf(x2.x, w0, fmaf(x2.y, w1, fmaf(x2.z, w2, fmaf(x2.w, w3, acc2))));
        acc3 = fmaf(x3.x, w0, fmaf(x3.y, w1, fmaf(x3.z, w2, fmaf(x3.w, w3, acc3))));
    }

    const float a1v = a[lane], a2v = a[FOUT + lane];
    float accs[4] = {acc0, acc1, acc2, acc3};
    #pragma unroll
    for (int r = 0; r < 4; ++r) {
        float v1 = accs[r] * a1v;
        float v2 = accs[r] * a2v;
        #pragma unroll
        for (int off = 32; off; off >>= 1) {
            v1 += __shfl_xor(v1, off);
            v2 += __shfl_xor(v2, off);
        }
        if (lane == 0) { s1[i0 + r0 + r] = v1; s2[i0 + r0 + r] = v2; }
        tile[lane][r0 + r] = f2bf(accs[r]);
    }
    __syncthreads();

    const int feat = threadIdx.x >> 2;
    const int cg   = (threadIdx.x & 3) * 4;
    uint2 q = *(const uint2*)&tile[feat][cg];
    *(uint2*)(htg + (size_t)feat * NN + i0 + cg) = q;
}

// ---------------- Kernel 2: async-staged fused attention + PV + normalize ---------
// Block: 16-row i-tile x ALL 8192 cols, 4 waves. Double-buffered global_load_lds
// streams raw adj tiles (16x512 int32 = 32KB) into LDS; compute phase reads ints
// from LDS in A-fragment order, does exp in-register, 5 MFMA per kk (4 feature
// blocks + denominator column). Epilogue: cross-wave reduce in LDS, normalize,
// ELU, write final output. 512 blocks = exactly 2 resident/CU (66KB LDS).
__global__ __launch_bounds__(256) void k_attn(
    const int* __restrict__ adj,
    const unsigned short* __restrict__ htg,
    const float* __restrict__ s1g, const float* __restrict__ s2g,
    float* __restrict__ out)
{
    __shared__ __align__(16) unsigned char smem[2 * BUF_BYTES];   // 66048 B

    const int t    = threadIdx.x;
    const int wid  = t >> 6;
    const int lane = t & 63;
    const int i0   = blockIdx.x * 16;
    const int m    = lane & 15;
    const int quad = lane >> 4;

    const float s1v = s1g[i0 + m];

    const short bd = (m == 0) ? (short)0x3F80 : (short)0;  // bf16 1.0 / 0
    const s16x8 bden = {bd, bd, bd, bd, bd, bd, bd, bd};

    f32x4 acc0 = {0,0,0,0}, acc1 = {0,0,0,0}, acc2 = {0,0,0,0},
          acc3 = {0,0,0,0}, acc4 = {0,0,0,0};

    // ---- prologue: stage tile 0 into buffer 0 ----
    {
        #pragma unroll
        for (int rr = 0; rr < 4; ++rr) {
            const int r = wid * 4 + rr;
            const int* g = adj + (size_t)(i0 + r) * NN + lane * 4;
            unsigned char* l = smem + r * ROW_PITCH;
            gl_lds16(g, l);
            gl_lds16(g + 256, l + 1024);
        }
    }
    __builtin_amdgcn_s_waitcnt(0);
    __syncthreads();

    for (int tl = 0; tl < NTILES; ++tl) {
        const unsigned char* buf = smem + (tl & 1) * BUF_BYTES;
        const int j0 = tl * TILE_COLS;

        // ---- issue async stage of tile tl+1 into the other buffer ----
        if (tl < NTILES - 1) {
            unsigned char* nbuf = smem + ((tl + 1) & 1) * BUF_BYTES;
            const int nj0 = (tl + 1) * TILE_COLS;
            #pragma unroll
            for (int rr = 0; rr < 4; ++rr) {
                const int r = wid * 4 + rr;
                const int* g = adj + (size_t)(i0 + r) * NN + nj0 + lane * 4;
                unsigned char* l = nbuf + r * ROW_PITCH;
                gl_lds16(g, l);
                gl_lds16(g + 256, l + 1024);
            }
        }

        // ---- compute tile tl: wave wid owns kk = wid*4 .. wid*4+3 ----
        #pragma unroll
        for (int kq = 0; kq < 4; ++kq) {
            const int kk = wid * 4 + kq;
            const unsigned char* ap = buf + m * ROW_PITCH + kk * 128 + quad * 32;
            i32x4 a0 = *(const i32x4*)(ap);
            i32x4 a1 = *(const i32x4*)(ap + 16);

            const int j = j0 + kk * 32 + quad * 8;
            float4 sa = *(const float4*)(s2g + j);
            float4 sb = *(const float4*)(s2g + j + 4);
            const unsigned short* hp = htg + (size_t)m * NN + j;
            s16x8 b0 = *(const s16x8*)(hp);
            s16x8 b1 = *(const s16x8*)(hp + (size_t)16 * NN);
            s16x8 b2 = *(const s16x8*)(hp + (size_t)32 * NN);
            s16x8 b3 = *(const s16x8*)(hp + (size_t)48 * NN);

            float x0 = s1v + sa.x, x1 = s1v + sa.y, x2 = s1v + sa.z, x3 = s1v + sa.w;
            float x4 = s1v + sb.x, x5 = s1v + sb.y, x6 = s1v + sb.z, x7 = s1v + sb.w;
            float w0 = (a0.x > 0) ? __expf(fmaxf(x0, ALPHA_SLOPE * x0)) : EXP_M10;
            float w1 = (a0.y > 0) ? __expf(fmaxf(x1, ALPHA_SLOPE * x1)) : EXP_M10;
            float w2 = (a0.z > 0) ? __expf(fmaxf(x2, ALPHA_SLOPE * x2)) : EXP_M10;
            float w3 = (a0.w > 0) ? __expf(fmaxf(x3, ALPHA_SLOPE * x3)) : EXP_M10;
            float w4 = (a1.x > 0) ? __expf(fmaxf(x4, ALPHA_SLOPE * x4)) : EXP_M10;
            float w5 = (a1.y > 0) ? __expf(fmaxf(x5, ALPHA_SLOPE * x5)) : EXP_M10;
            float w6 = (a1.z > 0) ? __expf(fmaxf(x6, ALPHA_SLOPE * x6)) : EXP_M10;
            float w7 = (a1.w > 0) ? __expf(fmaxf(x7, ALPHA_SLOPE * x7)) : EXP_M10;

            s16x8 af;
            af[0] = (short)f2bf(w0); af[1] = (short)f2bf(w1);
            af[2] = (short)f2bf(w2); af[3] = (short)f2bf(w3);
            af[4] = (short)f2bf(w4); af[5] = (short)f2bf(w5);
            af[6] = (short)f2bf(w6); af[7] = (short)f2bf(w7);

            acc0 = __builtin_amdgcn_mfma_f32_16x16x32_bf16(af, b0,   acc0, 0, 0, 0);
            acc1 = __builtin_amdgcn_mfma_f32_16x16x32_bf16(af, b1,   acc1, 0, 0, 0);
            acc2 = __builtin_amdgcn_mfma_f32_16x16x32_bf16(af, b2,   acc2, 0, 0, 0);
            acc3 = __builtin_amdgcn_mfma_f32_16x16x32_bf16(af, b3,   acc3, 0, 0, 0);
            acc4 = __builtin_amdgcn_mfma_f32_16x16x32_bf16(af, bden, acc4, 0, 0, 0);
        }

        // barrier: drains vmcnt (tile tl+1 arrived) + lgkm (all waves done with buf)
        __builtin_amdgcn_s_waitcnt(0);
        __syncthreads();
    }

    // ---- cross-wave kk-partial reduction, normalize, ELU, final store ----
    float* red = (float*)smem;               // 4 x 16 x CP floats = 17.4 KB
    float* myred = red + wid * 16 * CP;
    #pragma unroll
    for (int reg = 0; reg < 4; ++reg) {
        const int r = quad * 4 + reg;
        myred[r * CP +  0 + m] = acc0[reg];
        myred[r * CP + 16 + m] = acc1[reg];
        myred[r * CP + 32 + m] = acc2[reg];
        myred[r * CP + 48 + m] = acc3[reg];
        if (m == 0) myred[r * CP + 64] = acc4[reg];
    }
    __syncthreads();

    #pragma unroll
    for (int idx = t; idx < 16 * 64; idx += 256) {
        const int r = idx >> 6, c = idx & 63;
        float num = red[0 * 16 * CP + r * CP + c] + red[1 * 16 * CP + r * CP + c]
                  + red[2 * 16 * CP + r * CP + c] + red[3 * 16 * CP + r * CP + c];
        float den = red[0 * 16 * CP + r * CP + 64] + red[1 * 16 * CP + r * CP + 64]
                  + red[2 * 16 * CP + r * CP + 64] + red[3 * 16 * CP + r * CP + 64];
        float v = num / den;
        out[(size_t)(i0 + r) * FOUT + c] = (v > 0.f) ? v : (__expf(v) - 1.f);
    }
}

// ---------------- launch -----------------------------------------------------------
extern "C" void kernel_launch(void* const* d_in, const int* in_sizes, int n_in,
                              void* d_out, int out_size, void* d_ws, size_t ws_size,
                              hipStream_t stream) {
    const float* input = (const float*)d_in[0];
    const int*   adj   = (const int*)d_in[1];
    const float* W     = (const float*)d_in[2];
    const float* a     = (const float*)d_in[3];
    float* out = (float*)d_out;

    char* ws = (char*)d_ws;
    unsigned short* htg = (unsigned short*)ws;                  // 1 MB
    size_t off = (size_t)FOUT * NN * sizeof(unsigned short);
    float* s1 = (float*)(ws + off); off += NN * sizeof(float);
    float* s2 = (float*)(ws + off);

    k_h   <<<NN / 16, 256, 0, stream>>>(input, W, a, htg, s1, s2);
    k_attn<<<NN / 16, 256, 0, stream>>>(adj, htg, s1, s2, out);
}

// Round 7
// 391.280 us; speedup vs baseline: 1.2846x; 1.0713x over previous
//
#include <hip/hip_runtime.h>
#include <hip/hip_bf16.h>
#include <cstdint>
#include <cstddef>

#define NN 8192
#define FIN 256
#define FOUT 64
#define ALPHA_SLOPE 0.2f
#define EXP_M10 4.5399929762484854e-05f   // exp(-10)

#define JSPLIT 2
#define STRIP 128
#define NSTRIP ((NN / JSPLIT) / STRIP)    // 32
#define WPITCH 272                        // bytes per w-row in LDS (256 data + 16 pad)
#define HPITCH 272                        // bytes per htg-row in LDS
#define CP 68                             // slab column pitch (floats)

typedef short s16x8 __attribute__((ext_vector_type(8)));
typedef float f32x4 __attribute__((ext_vector_type(4)));
typedef int   i32x4 __attribute__((ext_vector_type(4)));

__device__ __forceinline__ unsigned short f2bf(float x) {
    union { float f; uint32_t u; } v; v.f = x;
    uint32_t u = v.u;
    return (unsigned short)((u + 0x7FFFu + ((u >> 16) & 1u)) >> 16);  // RNE
}

__device__ __forceinline__ unsigned int pk2(float lo, float hi) {
    return (unsigned int)f2bf(lo) | ((unsigned int)f2bf(hi) << 16);
}

// ---------------- Kernel 1: h = input@W, s1 = h@a1, s2 = h@a2, htg = bf16(h)^T ----
__global__ __launch_bounds__(256) void k_h(
    const float* __restrict__ input, const float* __restrict__ W,
    const float* __restrict__ a,
    unsigned short* __restrict__ htg, float* __restrict__ s1, float* __restrict__ s2)
{
    __shared__ __align__(16) unsigned short tile[64][28];
    const int wid  = threadIdx.x >> 6;
    const int lane = threadIdx.x & 63;
    const int i0   = blockIdx.x * 16;
    const int r0   = wid * 4;
    const float* inb = input + (size_t)(i0 + r0) * FIN;

    float acc0 = 0.f, acc1 = 0.f, acc2 = 0.f, acc3 = 0.f;
    #pragma unroll 4
    for (int c = 0; c < FIN; c += 4) {
        float w0 = W[(c + 0) * FOUT + lane];
        float w1 = W[(c + 1) * FOUT + lane];
        float w2 = W[(c + 2) * FOUT + lane];
        float w3 = W[(c + 3) * FOUT + lane];
        float4 x0 = *(const float4*)(inb + 0 * FIN + c);
        float4 x1 = *(const float4*)(inb + 1 * FIN + c);
        float4 x2 = *(const float4*)(inb + 2 * FIN + c);
        float4 x3 = *(const float4*)(inb + 3 * FIN + c);
        acc0 = fmaf(x0.x, w0, fmaf(x0.y, w1, fmaf(x0.z, w2, fmaf(x0.w, w3, acc0))));
        acc1 = fmaf(x1.x, w0, fmaf(x1.y, w1, fmaf(x1.z, w2, fmaf(x1.w, w3, acc1))));
        acc2 = fmaf(x2.x, w0, fmaf(x2.y, w1, fmaf(x2.z, w2, fmaf(x2.w, w3, acc2))));
        acc3 = fmaf(x3.x, w0, fmaf(x3.y, w1, fmaf(x3.z, w2, fmaf(x3.w, w3, acc3))));
    }

    const float a1v = a[lane], a2v = a[FOUT + lane];
    float accs[4] = {acc0, acc1, acc2, acc3};
    #pragma unroll
    for (int r = 0; r < 4; ++r) {
        float v1 = accs[r] * a1v;
        float v2 = accs[r] * a2v;
        #pragma unroll
        for (int off = 32; off; off >>= 1) {
            v1 += __shfl_xor(v1, off);
            v2 += __shfl_xor(v2, off);
        }
        if (lane == 0) { s1[i0 + r0 + r] = v1; s2[i0 + r0 + r] = v2; }
        tile[lane][r0 + r] = f2bf(accs[r]);
    }
    __syncthreads();

    const int feat = threadIdx.x >> 2;
    const int cg   = (threadIdx.x & 3) * 4;
    uint2 q = *(const uint2*)&tile[feat][cg];
    *(uint2*)(htg + (size_t)feat * NN + i0 + cg) = q;
}

// ---------------- Kernel 2: traffic-minimized fused attention ----------------------
// Block: 32 rows x 4096-col j-half, 512 threads (8 waves), 2 blocks/CU.
// Per 128-col strip (double-buffered, pipelined one ahead through VGPRs):
//   stage: w = bf16(exp(masked lrelu(s1_i+s2_j))) computed ONCE per element -> LDS;
//          htg strip (64 feats x 128 cols) -> LDS (shared by all 8 waves -> halves
//          the dominant htg re-read traffic vs 16-row blocks).
//   mfma : wave (rowgrp, kkpair, featgrp) does 2 kk x (2 or 3) MFMA from LDS.
// Epilogue: LDS reduction over kk-waves -> slab (denominator via B=[1,0..] MFMA).
__global__ __launch_bounds__(512, 4) void k_attn(
    const int* __restrict__ adj,
    const unsigned short* __restrict__ htg,
    const float* __restrict__ s1g, const float* __restrict__ s2g,
    float* __restrict__ slabs)
{
    __shared__ __align__(16) unsigned char wbuf[2][32 * WPITCH];   // 17408 B
    __shared__ __align__(16) unsigned char hbuf[2][64 * HPITCH];   // 34816 B

    const int t    = threadIdx.x;
    const int wid  = t >> 6;
    const int lane = t & 63;
    const int bi   = blockIdx.x >> 1;
    const int js   = blockIdx.x & 1;
    const int i0   = bi * 32;
    const int jbase = js * (NN / JSPLIT);
    const int m    = lane & 15;
    const int quad = lane >> 4;
    const int rg   = wid >> 2;          // row group: rows rg*16..rg*16+15
    const int kp   = (wid >> 1) & 1;    // kk pair: kk = kp*2 + {0,1}
    const int fg   = wid & 1;           // feature group: feats fg*32..fg*32+31 (+den)

    // fixed staging coordinates
    const int srow  = t >> 4;           // 0..31  (adj/w row)
    const int scol  = (t & 15) * 8;     // 0..120 (8 cols per thread)
    const int sfeat = t >> 3;           // 0..63  (htg row)
    const int scol2 = (t & 7) * 16;     // 0..112 (16 cols per thread)
    const float s1v = s1g[i0 + srow];

    const short bd = (m == 0) ? (short)0x3F80 : (short)0;   // bf16 1.0 / 0
    const s16x8 bden = {bd, bd, bd, bd, bd, bd, bd, bd};

    f32x4 accA = {0,0,0,0}, accB = {0,0,0,0}, accD = {0,0,0,0};

    const int* adjrow = adj + (size_t)(i0 + srow) * NN + jbase;
    const unsigned short* hrow = htg + (size_t)sfeat * NN + jbase;

    // ---- prologue: stage strip 0 into buffer 0 ----
    {
        i32x4  a0 = *(const i32x4*)(adjrow + scol);
        i32x4  a1 = *(const i32x4*)(adjrow + scol + 4);
        float4 v0 = *(const float4*)(s2g + jbase + scol);
        float4 v1 = *(const float4*)(s2g + jbase + scol + 4);
        s16x8  h0 = *(const s16x8*)(hrow + scol2);
        s16x8  h1 = *(const s16x8*)(hrow + scol2 + 8);

        float x0=s1v+v0.x, x1=s1v+v0.y, x2=s1v+v0.z, x3=s1v+v0.w;
        float x4=s1v+v1.x, x5=s1v+v1.y, x6=s1v+v1.z, x7=s1v+v1.w;
        float w0=(a0.x>0)?__expf(fmaxf(x0,ALPHA_SLOPE*x0)):EXP_M10;
        float w1=(a0.y>0)?__expf(fmaxf(x1,ALPHA_SLOPE*x1)):EXP_M10;
        float w2=(a0.z>0)?__expf(fmaxf(x2,ALPHA_SLOPE*x2)):EXP_M10;
        float w3=(a0.w>0)?__expf(fmaxf(x3,ALPHA_SLOPE*x3)):EXP_M10;
        float w4=(a1.x>0)?__expf(fmaxf(x4,ALPHA_SLOPE*x4)):EXP_M10;
        float w5=(a1.y>0)?__expf(fmaxf(x5,ALPHA_SLOPE*x5)):EXP_M10;
        float w6=(a1.z>0)?__expf(fmaxf(x6,ALPHA_SLOPE*x6)):EXP_M10;
        float w7=(a1.w>0)?__expf(fmaxf(x7,ALPHA_SLOPE*x7)):EXP_M10;
        uint4 pk = { pk2(w0,w1), pk2(w2,w3), pk2(w4,w5), pk2(w6,w7) };
        *(uint4*)&wbuf[0][srow * WPITCH + scol * 2] = pk;
        *(s16x8*)&hbuf[0][sfeat * HPITCH + scol2 * 2] = h0;
        *(s16x8*)&hbuf[0][sfeat * HPITCH + scol2 * 2 + 16] = h1;
    }
    __syncthreads();

    for (int s = 0; s < NSTRIP; ++s) {
        const int cur = s & 1, nxt = cur ^ 1;
        const bool more = (s + 1 < NSTRIP);

        // (a) issue next strip's global loads (no waits yet)
        i32x4 a0, a1; float4 v0, v1; s16x8 h0, h1;
        if (more) {
            const int j0n = (s + 1) * STRIP;
            a0 = *(const i32x4*)(adjrow + j0n + scol);
            a1 = *(const i32x4*)(adjrow + j0n + scol + 4);
            v0 = *(const float4*)(s2g + jbase + j0n + scol);
            v1 = *(const float4*)(s2g + jbase + j0n + scol + 4);
            h0 = *(const s16x8*)(hrow + j0n + scol2);
            h1 = *(const s16x8*)(hrow + j0n + scol2 + 8);
        }

        // (b) compute current strip from LDS
        #pragma unroll
        for (int kq = 0; kq < 2; ++kq) {
            const int kk = kp * 2 + kq;
            const int cb = (kk * 32 + quad * 8) * 2;   // byte col offset
            s16x8 af = *(const s16x8*)&wbuf[cur][(rg * 16 + m) * WPITCH + cb];
            const unsigned char* hb = &hbuf[cur][cb];
            if (fg == 0) {
                s16x8 b0 = *(const s16x8*)(hb + (m +  0) * HPITCH);
                s16x8 b1 = *(const s16x8*)(hb + (m + 16) * HPITCH);
                accA = __builtin_amdgcn_mfma_f32_16x16x32_bf16(af, b0, accA, 0, 0, 0);
                accB = __builtin_amdgcn_mfma_f32_16x16x32_bf16(af, b1, accB, 0, 0, 0);
            } else {
                s16x8 b2 = *(const s16x8*)(hb + (m + 32) * HPITCH);
                s16x8 b3 = *(const s16x8*)(hb + (m + 48) * HPITCH);
                accA = __builtin_amdgcn_mfma_f32_16x16x32_bf16(af, b2,   accA, 0, 0, 0);
                accB = __builtin_amdgcn_mfma_f32_16x16x32_bf16(af, b3,   accB, 0, 0, 0);
                accD = __builtin_amdgcn_mfma_f32_16x16x32_bf16(af, bden, accD, 0, 0, 0);
            }
        }

        // (c) finish staging next strip (waits for (a) loads happen here)
        if (more) {
            float x0=s1v+v0.x, x1=s1v+v0.y, x2=s1v+v0.z, x3=s1v+v0.w;
            float x4=s1v+v1.x, x5=s1v+v1.y, x6=s1v+v1.z, x7=s1v+v1.w;
            float w0=(a0.x>0)?__expf(fmaxf(x0,ALPHA_SLOPE*x0)):EXP_M10;
            float w1=(a0.y>0)?__expf(fmaxf(x1,ALPHA_SLOPE*x1)):EXP_M10;
            float w2=(a0.z>0)?__expf(fmaxf(x2,ALPHA_SLOPE*x2)):EXP_M10;
            float w3=(a0.w>0)?__expf(fmaxf(x3,ALPHA_SLOPE*x3)):EXP_M10;
            float w4=(a1.x>0)?__expf(fmaxf(x4,ALPHA_SLOPE*x4)):EXP_M10;
            float w5=(a1.y>0)?__expf(fmaxf(x5,ALPHA_SLOPE*x5)):EXP_M10;
            float w6=(a1.z>0)?__expf(fmaxf(x6,ALPHA_SLOPE*x6)):EXP_M10;
            float w7=(a1.w>0)?__expf(fmaxf(x7,ALPHA_SLOPE*x7)):EXP_M10;
            uint4 pk = { pk2(w0,w1), pk2(w2,w3), pk2(w4,w5), pk2(w6,w7) };
            *(uint4*)&wbuf[nxt][srow * WPITCH + scol * 2] = pk;
            *(s16x8*)&hbuf[nxt][sfeat * HPITCH + scol2 * 2] = h0;
            *(s16x8*)&hbuf[nxt][sfeat * HPITCH + scol2 * 2 + 16] = h1;
        }
        __syncthreads();
    }

    // ---- epilogue: reduce kk-pair waves, write slab ----
    // red[8][16][34] floats = 17408 B, overlaid on hbuf (all reads done: final barrier passed)
    float* red = (float*)hbuf;
    float* myr = red + wid * (16 * 34);
    #pragma unroll
    for (int reg = 0; reg < 4; ++reg) {
        const int r = quad * 4 + reg;
        myr[r * 34 + m]      = accA[reg];
        myr[r * 34 + 16 + m] = accB[reg];
        if (fg == 1 && m == 0) myr[r * 34 + 32] = accD[reg];
    }
    __syncthreads();

    float* slab = slabs + (size_t)js * ((size_t)NN * CP);
    #pragma unroll
    for (int idx = t; idx < 32 * 64; idx += 512) {
        const int r = idx >> 6, c = idx & 63;
        const int rg2 = r >> 4, rr = r & 15;
        const int fg2 = c >> 5, lc = c & 31;
        float num = red[(rg2 * 4 + 0 + fg2) * 544 + rr * 34 + lc]
                  + red[(rg2 * 4 + 2 + fg2) * 544 + rr * 34 + lc];
        slab[(size_t)(i0 + r) * CP + c] = num;
        if (c == 0) {
            float den = red[(rg2 * 4 + 1) * 544 + rr * 34 + 32]
                      + red[(rg2 * 4 + 3) * 544 + rr * 34 + 32];
            slab[(size_t)(i0 + r) * CP + 64] = den;
        }
    }
}

// ---------------- Kernel 3: reduce splits, normalize, ELU --------------------------
__global__ __launch_bounds__(256) void k_norm(
    const float* __restrict__ slabs, float* __restrict__ out)
{
    int gid = blockIdx.x * 256 + threadIdx.x;
    int i = gid >> 6, k = gid & 63;
    float num = 0.f, den = 0.f;
    #pragma unroll
    for (int js = 0; js < JSPLIT; ++js) {
        const float* row = slabs + (size_t)js * ((size_t)NN * CP) + (size_t)i * CP;
        num += row[k];
        den += row[64];
    }
    float v = num / den;
    out[gid] = (v > 0.f) ? v : (__expf(v) - 1.f);
}

// ---------------- launch -----------------------------------------------------------
extern "C" void kernel_launch(void* const* d_in, const int* in_sizes, int n_in,
                              void* d_out, int out_size, void* d_ws, size_t ws_size,
                              hipStream_t stream) {
    const float* input = (const float*)d_in[0];
    const int*   adj   = (const int*)d_in[1];
    const float* W     = (const float*)d_in[2];
    const float* a     = (const float*)d_in[3];
    float* out = (float*)d_out;

    char* ws = (char*)d_ws;
    float* slabs = (float*)ws;
    size_t off = (size_t)JSPLIT * NN * CP * sizeof(float);      // 4.5 MB
    unsigned short* htg = (unsigned short*)(ws + off);
    off += (size_t)FOUT * NN * sizeof(unsigned short);          // 1 MB
    float* s1 = (float*)(ws + off); off += NN * sizeof(float);
    float* s2 = (float*)(ws + off);

    k_h   <<<NN / 16, 256, 0, stream>>>(input, W, a, htg, s1, s2);
    k_attn<<<(NN / 32) * JSPLIT, 512, 0, stream>>>(adj, htg, s1, s2, slabs);
    k_norm<<<NN * FOUT / 256, 256, 0, stream>>>(slabs, out);
}